// Round 1
// baseline (478.997 us; speedup 1.0000x reference)
//
#include <hip/hip_runtime.h>
#include <math.h>

#define NS 2048
#define NT 2048
#define NATOMS 128
#define NITER 50

#define BS 64     // mobile structures per block tile
#define BT 32     // target structures per block tile
#define KT 32     // atoms per K-step
#define PAD_K 36  // padded LDS row stride (float4-aligned, conflict-mitigating)

// ---------------- Stage A: center + squared norms ----------------
__global__ __launch_bounds__(64) void center_norm_kernel(
    const float* __restrict__ X, float* __restrict__ Xc, float* __restrict__ norms)
{
    const int s = blockIdx.x;
    const int lane = threadIdx.x;  // 64 lanes, 2 atoms each
    const float* xs = X + (size_t)s * (NATOMS * 3);
    float x0 = xs[lane * 3 + 0];
    float y0 = xs[lane * 3 + 1];
    float z0 = xs[lane * 3 + 2];
    float x1 = xs[(lane + 64) * 3 + 0];
    float y1 = xs[(lane + 64) * 3 + 1];
    float z1 = xs[(lane + 64) * 3 + 2];
    float sx = x0 + x1, sy = y0 + y1, sz = z0 + z1;
#pragma unroll
    for (int off = 32; off > 0; off >>= 1) {
        sx += __shfl_xor(sx, off);
        sy += __shfl_xor(sy, off);
        sz += __shfl_xor(sz, off);
    }
    const float inv_n = 1.0f / (float)NATOMS;
    const float mx = sx * inv_n, my = sy * inv_n, mz = sz * inv_n;
    x0 -= mx; y0 -= my; z0 -= mz;
    x1 -= mx; y1 -= my; z1 -= mz;
    float* xc = Xc + (size_t)s * (NATOMS * 3);  // layout [s][3][128]
    xc[0 * NATOMS + lane] = x0;
    xc[0 * NATOMS + 64 + lane] = x1;
    xc[1 * NATOMS + lane] = y0;
    xc[1 * NATOMS + 64 + lane] = y1;
    xc[2 * NATOMS + lane] = z0;
    xc[2 * NATOMS + 64 + lane] = z1;
    float nsq = x0 * x0 + y0 * y0 + z0 * z0 + x1 * x1 + y1 * y1 + z1 * z1;
#pragma unroll
    for (int off = 32; off > 0; off >>= 1) nsq += __shfl_xor(nsq, off);
    if (lane == 0) norms[s] = nsq;
}

// ---------------- Stage B: pair tile kernel ----------------
__global__ __launch_bounds__(256, 2) void pair_kernel(
    const float* __restrict__ Am,      // [NS][3][128] centered mobile
    const float* __restrict__ Bm,      // [NT][3][128] centered target
    const float* __restrict__ norm_s,
    const float* __restrict__ norm_t,
    float* __restrict__ out)           // [NS][NT]
{
    __shared__ float As[3 * BS * PAD_K];
    __shared__ float Bs[3 * BT * PAD_K];

    const int tid = threadIdx.x;
    const int tx = tid & 15;   // target group: 16 x 2
    const int ty = tid >> 4;   // mobile group: 16 x 4
    const int sBase = blockIdx.x * BS;
    const int tBase = blockIdx.y * BT;

    float acc[4][2][9];
#pragma unroll
    for (int u = 0; u < 4; ++u)
#pragma unroll
        for (int v = 0; v < 2; ++v)
#pragma unroll
            for (int c = 0; c < 9; ++c) acc[u][v][c] = 0.0f;

    for (int kb = 0; kb < NATOMS; kb += KT) {
        __syncthreads();
        // Load A tile: 3*BS rows of KT floats (as float4s)
        {
            const int nf4 = 3 * BS * (KT / 4);  // 1536
            for (int f4 = tid; f4 < nf4; f4 += 256) {
                const int r  = f4 >> 3;     // row 0..191
                const int k4 = f4 & 7;
                const int i  = r >> 6;      // component
                const int ss = r & 63;      // local structure
                float4 val = *reinterpret_cast<const float4*>(
                    Am + (size_t)(sBase + ss) * (3 * NATOMS) + i * NATOMS + kb + k4 * 4);
                *reinterpret_cast<float4*>(&As[(i * BS + ss) * PAD_K + k4 * 4]) = val;
            }
        }
        // Load B tile
        {
            const int nf4 = 3 * BT * (KT / 4);  // 768
            for (int f4 = tid; f4 < nf4; f4 += 256) {
                const int r  = f4 >> 3;     // row 0..95
                const int k4 = f4 & 7;
                const int j  = r >> 5;
                const int tt = r & 31;
                float4 val = *reinterpret_cast<const float4*>(
                    Bm + (size_t)(tBase + tt) * (3 * NATOMS) + j * NATOMS + kb + k4 * 4);
                *reinterpret_cast<float4*>(&Bs[(j * BT + tt) * PAD_K + k4 * 4]) = val;
            }
        }
        __syncthreads();

#pragma unroll 2
        for (int kk = 0; kk < KT; kk += 4) {
            float4 a4[4][3];
            float4 b4[2][3];
#pragma unroll
            for (int u = 0; u < 4; ++u)
#pragma unroll
                for (int i = 0; i < 3; ++i)
                    a4[u][i] = *reinterpret_cast<const float4*>(
                        &As[(i * BS + ty * 4 + u) * PAD_K + kk]);
#pragma unroll
            for (int v = 0; v < 2; ++v)
#pragma unroll
                for (int j = 0; j < 3; ++j)
                    b4[v][j] = *reinterpret_cast<const float4*>(
                        &Bs[(j * BT + tx * 2 + v) * PAD_K + kk]);
#pragma unroll
            for (int u = 0; u < 4; ++u)
#pragma unroll
                for (int v = 0; v < 2; ++v)
#pragma unroll
                    for (int i = 0; i < 3; ++i)
#pragma unroll
                        for (int j = 0; j < 3; ++j) {
                            float sum = acc[u][v][i * 3 + j];
                            sum += a4[u][i].x * b4[v][j].x;
                            sum += a4[u][i].y * b4[v][j].y;
                            sum += a4[u][i].z * b4[v][j].z;
                            sum += a4[u][i].w * b4[v][j].w;
                            acc[u][v][i * 3 + j] = sum;
                        }
        }
    }

    // ---- Epilogue: build F, shifted power iteration (8 pairs interleaved) ----
    // P[u][v]: {D0,D1,D2,D3 (shifted diag), F01,F02,F03,F12,F13,F23, fro}
    float P[4][2][11];
    float vv[4][2][4];
#pragma unroll
    for (int u = 0; u < 4; ++u)
#pragma unroll
        for (int v = 0; v < 2; ++v) {
            const float* R = acc[u][v];
            // R[c]: c = i*3+j
            const float F00 =  R[0] + R[4] + R[8];
            const float F11 =  R[0] - R[4] - R[8];
            const float F22 = -R[0] + R[4] - R[8];
            const float F33 = -R[0] - R[4] + R[8];
            const float F01 = R[5] - R[7];
            const float F02 = R[6] - R[2];
            const float F03 = R[1] - R[3];
            const float F12 = R[1] + R[3];
            const float F13 = R[2] + R[6];
            const float F23 = R[5] + R[7];
            const float fro = sqrtf(F00 * F00 + F11 * F11 + F22 * F22 + F33 * F33 +
                                    2.0f * (F01 * F01 + F02 * F02 + F03 * F03 +
                                            F12 * F12 + F13 * F13 + F23 * F23));
            P[u][v][0] = F00 + fro;
            P[u][v][1] = F11 + fro;
            P[u][v][2] = F22 + fro;
            P[u][v][3] = F33 + fro;
            P[u][v][4] = F01;
            P[u][v][5] = F02;
            P[u][v][6] = F03;
            P[u][v][7] = F12;
            P[u][v][8] = F13;
            P[u][v][9] = F23;
            P[u][v][10] = fro;
            vv[u][v][0] = 0.5f; vv[u][v][1] = 0.5f;
            vv[u][v][2] = 0.5f; vv[u][v][3] = 0.5f;
        }

    for (int it = 0; it < NITER; ++it) {
#pragma unroll
        for (int u = 0; u < 4; ++u)
#pragma unroll
            for (int v = 0; v < 2; ++v) {
                float* F = P[u][v];
                float* q = vv[u][v];
                const float w0 = F[0] * q[0] + F[4] * q[1] + F[5] * q[2] + F[6] * q[3];
                const float w1 = F[4] * q[0] + F[1] * q[1] + F[7] * q[2] + F[8] * q[3];
                const float w2 = F[5] * q[0] + F[7] * q[1] + F[2] * q[2] + F[9] * q[3];
                const float w3 = F[6] * q[0] + F[8] * q[1] + F[9] * q[2] + F[3] * q[3];
                const float inv = 1.0f /
                    (sqrtf(w0 * w0 + w1 * w1 + w2 * w2 + w3 * w3) + 1e-12f);
                q[0] = w0 * inv; q[1] = w1 * inv; q[2] = w2 * inv; q[3] = w3 * inv;
            }
    }

    const float inv_na = 1.0f / (128.0f + 1e-5f);
#pragma unroll
    for (int u = 0; u < 4; ++u) {
        const int srow = sBase + ty * 4 + u;
        const float nm = norm_s[srow];
#pragma unroll
        for (int v = 0; v < 2; ++v) {
            const int tcol = tBase + tx * 2 + v;
            const float* F = P[u][v];
            const float* q = vv[u][v];
            // Rayleigh quotient with unshifted F: subtract fro (||v||~=1)
            const float eig =
                F[0] * q[0] * q[0] + F[1] * q[1] * q[1] +
                F[2] * q[2] * q[2] + F[3] * q[3] * q[3] +
                2.0f * (q[0] * (F[4] * q[1] + F[5] * q[2] + F[6] * q[3]) +
                        q[1] * (F[7] * q[2] + F[8] * q[3]) +
                        F[9] * q[2] * q[3]) -
                F[10];
            float sq = (nm + norm_t[tcol] - 2.0f * eig) * inv_na;
            sq = fmaxf(sq, 0.0f);
            out[(size_t)srow * NT + tcol] = sqrtf(sq);
        }
    }
}

extern "C" void kernel_launch(void* const* d_in, const int* in_sizes, int n_in,
                              void* d_out, int out_size, void* d_ws, size_t ws_size,
                              hipStream_t stream) {
    const float* Xm = (const float*)d_in[0];
    const float* Xt = (const float*)d_in[1];
    float* out = (float*)d_out;
    float* ws = (float*)d_ws;

    float* Xcm    = ws;                        // 2048*384 floats
    float* Xct    = ws + (size_t)NS * 384;     // 2048*384 floats
    float* norm_m = ws + (size_t)2 * NS * 384; // 2048
    float* norm_t = norm_m + NS;               // 2048

    center_norm_kernel<<<NS, 64, 0, stream>>>(Xm, Xcm, norm_m);
    center_norm_kernel<<<NT, 64, 0, stream>>>(Xt, Xct, norm_t);

    dim3 grid(NS / BS, NT / BT);
    pair_kernel<<<grid, 256, 0, stream>>>(Xcm, Xct, norm_m, norm_t, out);
}

// Round 3
// 255.935 us; speedup vs baseline: 1.8716x; 1.8716x over previous
//
#include <hip/hip_runtime.h>
#include <math.h>

#define NS 2048
#define NT 2048
#define NATOMS 128
#define NITER 50

#define BS 64     // mobile structures per block tile
#define BT 32     // target structures per block tile
#define KT 32     // atoms per K-step
#define PAD_K 36  // padded LDS row stride

// ---------------- Stage A: center + squared norms ----------------
__global__ __launch_bounds__(64) void center_norm_kernel(
    const float* __restrict__ X, float* __restrict__ Xc, float* __restrict__ norms)
{
    const int s = blockIdx.x;
    const int lane = threadIdx.x;  // 64 lanes, 2 atoms each
    const float* xs = X + (size_t)s * (NATOMS * 3);
    float x0 = xs[lane * 3 + 0];
    float y0 = xs[lane * 3 + 1];
    float z0 = xs[lane * 3 + 2];
    float x1 = xs[(lane + 64) * 3 + 0];
    float y1 = xs[(lane + 64) * 3 + 1];
    float z1 = xs[(lane + 64) * 3 + 2];
    float sx = x0 + x1, sy = y0 + y1, sz = z0 + z1;
#pragma unroll
    for (int off = 32; off > 0; off >>= 1) {
        sx += __shfl_xor(sx, off);
        sy += __shfl_xor(sy, off);
        sz += __shfl_xor(sz, off);
    }
    const float inv_n = 1.0f / (float)NATOMS;
    const float mx = sx * inv_n, my = sy * inv_n, mz = sz * inv_n;
    x0 -= mx; y0 -= my; z0 -= mz;
    x1 -= mx; y1 -= my; z1 -= mz;
    float* xc = Xc + (size_t)s * (NATOMS * 3);  // layout [s][3][128]
    xc[0 * NATOMS + lane] = x0;
    xc[0 * NATOMS + 64 + lane] = x1;
    xc[1 * NATOMS + lane] = y0;
    xc[1 * NATOMS + 64 + lane] = y1;
    xc[2 * NATOMS + lane] = z0;
    xc[2 * NATOMS + 64 + lane] = z1;
    float nsq = x0 * x0 + y0 * y0 + z0 * z0 + x1 * x1 + y1 * y1 + z1 * z1;
#pragma unroll
    for (int off = 32; off > 0; off >>= 1) nsq += __shfl_xor(nsq, off);
    if (lane == 0) norms[s] = nsq;
}

// ---------------- Stage B: pair tile kernel ----------------
__global__ __launch_bounds__(256, 1) void pair_kernel(
    const float* __restrict__ Am,      // [NS][3][128] centered mobile
    const float* __restrict__ Bm,      // [NT][3][128] centered target
    const float* __restrict__ norm_s,
    const float* __restrict__ norm_t,
    float* __restrict__ out)           // [NS][NT]
{
    __shared__ float As[3 * BS * PAD_K];
    __shared__ float Bs[3 * BT * PAD_K];

    const int tid = threadIdx.x;
    const int tx = tid & 15;   // target lane group
    const int ty = tid >> 4;   // mobile lane group
    const int sBase = blockIdx.x * BS;
    const int tBase = blockIdx.y * BT;

    // Fragment rows: A row = u*16 + ty (u=0..3), B row = v*16 + tx (v=0..1).
    // A: 4 distinct LDS addrs/wave at stride 16*36 -> bank-quads 0/4/8/12: conflict-free.
    // B: 16 distinct addrs at stride 36 -> 2-way: free.
    float acc[4][2][9];
#pragma unroll
    for (int u = 0; u < 4; ++u)
#pragma unroll
        for (int v = 0; v < 2; ++v)
#pragma unroll
            for (int c = 0; c < 9; ++c) acc[u][v][c] = 0.0f;

    for (int kb = 0; kb < NATOMS; kb += KT) {
        __syncthreads();
        // Load A tile: 3*BS rows of KT floats (as float4s)
        {
            const int nf4 = 3 * BS * (KT / 4);  // 1536
            for (int f4 = tid; f4 < nf4; f4 += 256) {
                const int r  = f4 >> 3;     // row 0..191
                const int k4 = f4 & 7;
                const int i  = r >> 6;      // component
                const int ss = r & 63;      // local structure
                float4 val = *reinterpret_cast<const float4*>(
                    Am + (size_t)(sBase + ss) * (3 * NATOMS) + i * NATOMS + kb + k4 * 4);
                *reinterpret_cast<float4*>(&As[(i * BS + ss) * PAD_K + k4 * 4]) = val;
            }
        }
        // Load B tile
        {
            const int nf4 = 3 * BT * (KT / 4);  // 768
            for (int f4 = tid; f4 < nf4; f4 += 256) {
                const int r  = f4 >> 3;     // row 0..95
                const int k4 = f4 & 7;
                const int j  = r >> 5;
                const int tt = r & 31;
                float4 val = *reinterpret_cast<const float4*>(
                    Bm + (size_t)(tBase + tt) * (3 * NATOMS) + j * NATOMS + kb + k4 * 4);
                *reinterpret_cast<float4*>(&Bs[(j * BT + tt) * PAD_K + k4 * 4]) = val;
            }
        }
        __syncthreads();

#pragma unroll 2
        for (int kk = 0; kk < KT; kk += 4) {
            float4 a4[4][3];
            float4 b4[2][3];
#pragma unroll
            for (int u = 0; u < 4; ++u)
#pragma unroll
                for (int i = 0; i < 3; ++i)
                    a4[u][i] = *reinterpret_cast<const float4*>(
                        &As[(i * BS + u * 16 + ty) * PAD_K + kk]);
#pragma unroll
            for (int v = 0; v < 2; ++v)
#pragma unroll
                for (int j = 0; j < 3; ++j)
                    b4[v][j] = *reinterpret_cast<const float4*>(
                        &Bs[(j * BT + v * 16 + tx) * PAD_K + kk]);
#pragma unroll
            for (int u = 0; u < 4; ++u)
#pragma unroll
                for (int v = 0; v < 2; ++v)
#pragma unroll
                    for (int i = 0; i < 3; ++i)
#pragma unroll
                        for (int j = 0; j < 3; ++j) {
                            float sum = acc[u][v][i * 3 + j];
                            sum += a4[u][i].x * b4[v][j].x;
                            sum += a4[u][i].y * b4[v][j].y;
                            sum += a4[u][i].z * b4[v][j].z;
                            sum += a4[u][i].w * b4[v][j].w;
                            acc[u][v][i * 3 + j] = sum;
                        }
        }
    }

    // ---- Epilogue: shifted power iteration, 8 pairs interleaved, lazy norm ----
    // P[u][v]: {D0,D1,D2,D3 (shifted diag), F01,F02,F03,F12,F13,F23, fro}
    float P[4][2][11];
    float vv[4][2][4];
#pragma unroll
    for (int u = 0; u < 4; ++u)
#pragma unroll
        for (int v = 0; v < 2; ++v) {
            const float* R = acc[u][v];
            const float F00 =  R[0] + R[4] + R[8];
            const float F11 =  R[0] - R[4] - R[8];
            const float F22 = -R[0] + R[4] - R[8];
            const float F33 = -R[0] - R[4] + R[8];
            const float F01 = R[5] - R[7];
            const float F02 = R[6] - R[2];
            const float F03 = R[1] - R[3];
            const float F12 = R[1] + R[3];
            const float F13 = R[2] + R[6];
            const float F23 = R[5] + R[7];
            const float fro = sqrtf(F00 * F00 + F11 * F11 + F22 * F22 + F33 * F33 +
                                    2.0f * (F01 * F01 + F02 * F02 + F03 * F03 +
                                            F12 * F12 + F13 * F13 + F23 * F23));
            P[u][v][0] = F00 + fro;
            P[u][v][1] = F11 + fro;
            P[u][v][2] = F22 + fro;
            P[u][v][3] = F33 + fro;
            P[u][v][4] = F01;
            P[u][v][5] = F02;
            P[u][v][6] = F03;
            P[u][v][7] = F12;
            P[u][v][8] = F13;
            P[u][v][9] = F23;
            P[u][v][10] = fro;
            vv[u][v][0] = 0.5f; vv[u][v][1] = 0.5f;
            vv[u][v][2] = 0.5f; vv[u][v][3] = 0.5f;
        }

    // 50 matvecs; normalization is direction-preserving so do it every 5th
    // iteration (keeps fp32 magnitude in range; spectral radius <= 2*fro).
    for (int it = 0; it < NITER; ++it) {
#pragma unroll
        for (int u = 0; u < 4; ++u)
#pragma unroll
            for (int v = 0; v < 2; ++v) {
                float* F = P[u][v];
                float* q = vv[u][v];
                const float w0 = F[0] * q[0] + F[4] * q[1] + F[5] * q[2] + F[6] * q[3];
                const float w1 = F[4] * q[0] + F[1] * q[1] + F[7] * q[2] + F[8] * q[3];
                const float w2 = F[5] * q[0] + F[7] * q[1] + F[2] * q[2] + F[9] * q[3];
                const float w3 = F[6] * q[0] + F[8] * q[1] + F[9] * q[2] + F[3] * q[3];
                q[0] = w0; q[1] = w1; q[2] = w2; q[3] = w3;
            }
        if ((it % 5) == 4) {
#pragma unroll
            for (int u = 0; u < 4; ++u)
#pragma unroll
                for (int v = 0; v < 2; ++v) {
                    float* q = vv[u][v];
                    const float nn = q[0] * q[0] + q[1] * q[1] +
                                     q[2] * q[2] + q[3] * q[3];
                    const float sc = __builtin_amdgcn_rsqf(nn);
                    q[0] *= sc; q[1] *= sc; q[2] *= sc; q[3] *= sc;
                }
        }
    }

    const float inv_na = 1.0f / (128.0f + 1e-5f);
#pragma unroll
    for (int u = 0; u < 4; ++u) {
        const int srow = sBase + u * 16 + ty;
        const float nm = norm_s[srow];
#pragma unroll
        for (int v = 0; v < 2; ++v) {
            const int tcol = tBase + v * 16 + tx;
            const float* F = P[u][v];
            const float* q = vv[u][v];
            // Rayleigh quotient: (q^T F_shift q)/(q^T q) - fro
            const float m0 = F[0] * q[0] + F[4] * q[1] + F[5] * q[2] + F[6] * q[3];
            const float m1 = F[4] * q[0] + F[1] * q[1] + F[7] * q[2] + F[8] * q[3];
            const float m2 = F[5] * q[0] + F[7] * q[1] + F[2] * q[2] + F[9] * q[3];
            const float m3 = F[6] * q[0] + F[8] * q[1] + F[9] * q[2] + F[3] * q[3];
            const float num = q[0] * m0 + q[1] * m1 + q[2] * m2 + q[3] * m3;
            const float den = q[0] * q[0] + q[1] * q[1] + q[2] * q[2] + q[3] * q[3];
            const float eig = num * __builtin_amdgcn_rcpf(den) - F[10];
            float sq = (nm + norm_t[tcol] - 2.0f * eig) * inv_na;
            sq = fmaxf(sq, 0.0f);
            out[(size_t)srow * NT + tcol] = sqrtf(sq);
        }
    }
}

extern "C" void kernel_launch(void* const* d_in, const int* in_sizes, int n_in,
                              void* d_out, int out_size, void* d_ws, size_t ws_size,
                              hipStream_t stream) {
    const float* Xm = (const float*)d_in[0];
    const float* Xt = (const float*)d_in[1];
    float* out = (float*)d_out;
    float* ws = (float*)d_ws;

    float* Xcm    = ws;                        // 2048*384 floats
    float* Xct    = ws + (size_t)NS * 384;     // 2048*384 floats
    float* norm_m = ws + (size_t)2 * NS * 384; // 2048
    float* norm_t = norm_m + NS;               // 2048

    center_norm_kernel<<<NS, 64, 0, stream>>>(Xm, Xcm, norm_m);
    center_norm_kernel<<<NT, 64, 0, stream>>>(Xt, Xct, norm_t);

    dim3 grid(NS / BS, NT / BT);
    pair_kernel<<<grid, 256, 0, stream>>>(Xcm, Xct, norm_m, norm_t, out);
}

// Round 4
// 150.044 us; speedup vs baseline: 3.1924x; 1.7057x over previous
//
#include <hip/hip_runtime.h>
#include <math.h>

#define NS 2048
#define NT 2048
#define NATOMS 128

typedef __attribute__((ext_vector_type(8))) short bf16x8;
typedef __attribute__((ext_vector_type(4))) float f32x4;

static __device__ __forceinline__ unsigned short f2bf(float f) {
    unsigned int u = __float_as_uint(f);
    unsigned int r = (u + 0x7fffu + ((u >> 16) & 1u)) >> 16;  // RNE
    return (unsigned short)r;
}
static __device__ __forceinline__ float bf2f(unsigned short h) {
    return __uint_as_float(((unsigned int)h) << 16);
}

// ---------------- Stage A: center + hi/lo bf16 split + squared norms ----------------
__global__ __launch_bounds__(64) void center_bf16_kernel(
    const float* __restrict__ X, unsigned short* __restrict__ Hi,
    unsigned short* __restrict__ Lo, float* __restrict__ norms)
{
    const int s = blockIdx.x;
    const int lane = threadIdx.x;  // 64 lanes, 2 atoms each
    const float* xs = X + (size_t)s * (NATOMS * 3);
    float x0 = xs[lane * 3 + 0];
    float y0 = xs[lane * 3 + 1];
    float z0 = xs[lane * 3 + 2];
    float x1 = xs[(lane + 64) * 3 + 0];
    float y1 = xs[(lane + 64) * 3 + 1];
    float z1 = xs[(lane + 64) * 3 + 2];
    float sx = x0 + x1, sy = y0 + y1, sz = z0 + z1;
#pragma unroll
    for (int off = 32; off > 0; off >>= 1) {
        sx += __shfl_xor(sx, off);
        sy += __shfl_xor(sy, off);
        sz += __shfl_xor(sz, off);
    }
    const float inv_n = 1.0f / (float)NATOMS;
    const float mx = sx * inv_n, my = sy * inv_n, mz = sz * inv_n;
    x0 -= mx; y0 -= my; z0 -= mz;
    x1 -= mx; y1 -= my; z1 -= mz;

    const size_t base = (size_t)s * 384;   // [s][3][128] bf16
    const float v[3][2] = {{x0, x1}, {y0, y1}, {z0, z1}};
#pragma unroll
    for (int c = 0; c < 3; ++c)
#pragma unroll
        for (int h = 0; h < 2; ++h) {
            const unsigned short hb = f2bf(v[c][h]);
            const unsigned short lb = f2bf(v[c][h] - bf2f(hb));
            Hi[base + c * 128 + h * 64 + lane] = hb;
            Lo[base + c * 128 + h * 64 + lane] = lb;
        }

    float nsq = x0 * x0 + y0 * y0 + z0 * z0 + x1 * x1 + y1 * y1 + z1 * z1;
#pragma unroll
    for (int off = 32; off > 0; off >>= 1) nsq += __shfl_xor(nsq, off);
    if (lane == 0) norms[s] = nsq;
}

// ---------------- Stage B: MFMA covariance + per-lane power iteration ----------------
// Wave computes a 16x16 (s,t) tile: 9 MFMA accumulators R_ij; C-layout puts the
// full 3x3 R for 4 pairs in each lane; power iteration runs entirely in registers.
__global__ __launch_bounds__(256, 1) void pair_mfma_kernel(
    const unsigned short* __restrict__ Ahi, const unsigned short* __restrict__ Alo,
    const unsigned short* __restrict__ Bhi, const unsigned short* __restrict__ Blo,
    const float* __restrict__ norm_s, const float* __restrict__ norm_t,
    float* __restrict__ out)
{
    const int tid = threadIdx.x;
    const int wave = tid >> 6;
    const int lane = tid & 63;
    const int nrow = lane & 15;   // A m-row / B n-col / C col
    const int kgrp = lane >> 4;   // k-octet selector
    const int sBase = blockIdx.x * 16;
    const int tBase = blockIdx.y * 64 + wave * 16;

    // [s][3][128] bf16; lane reads 8 consecutive atoms at k = ks*32 + kgrp*8
    const size_t aOff = (size_t)(sBase + nrow) * 384 + kgrp * 8;
    const size_t bOff = (size_t)(tBase + nrow) * 384 + kgrp * 8;

    f32x4 acc[3][3];
#pragma unroll
    for (int i = 0; i < 3; ++i)
#pragma unroll
        for (int j = 0; j < 3; ++j) acc[i][j] = (f32x4){0.f, 0.f, 0.f, 0.f};

#pragma unroll
    for (int ks = 0; ks < 4; ++ks) {
        bf16x8 ah[3], al[3], bh[3], bl[3];
#pragma unroll
        for (int c = 0; c < 3; ++c) {
            ah[c] = *reinterpret_cast<const bf16x8*>(Ahi + aOff + c * 128 + ks * 32);
            al[c] = *reinterpret_cast<const bf16x8*>(Alo + aOff + c * 128 + ks * 32);
            bh[c] = *reinterpret_cast<const bf16x8*>(Bhi + bOff + c * 128 + ks * 32);
            bl[c] = *reinterpret_cast<const bf16x8*>(Blo + bOff + c * 128 + ks * 32);
        }
        // pass-outer ordering: each acc touched once per 9 MFMAs (latency hiding)
#pragma unroll
        for (int i = 0; i < 3; ++i)
#pragma unroll
            for (int j = 0; j < 3; ++j)
                acc[i][j] = __builtin_amdgcn_mfma_f32_16x16x32_bf16(
                    ah[i], bh[j], acc[i][j], 0, 0, 0);
#pragma unroll
        for (int i = 0; i < 3; ++i)
#pragma unroll
            for (int j = 0; j < 3; ++j)
                acc[i][j] = __builtin_amdgcn_mfma_f32_16x16x32_bf16(
                    ah[i], bl[j], acc[i][j], 0, 0, 0);
#pragma unroll
        for (int i = 0; i < 3; ++i)
#pragma unroll
            for (int j = 0; j < 3; ++j)
                acc[i][j] = __builtin_amdgcn_mfma_f32_16x16x32_bf16(
                    al[i], bh[j], acc[i][j], 0, 0, 0);
    }

    // ---- Per-lane: build shifted F for 4 pairs, 50 matvecs, lazy normalize ----
    float P[4][11];
    float vv[4][4];
#pragma unroll
    for (int u = 0; u < 4; ++u) {
        const float Sxx = acc[0][0][u], Sxy = acc[0][1][u], Sxz = acc[0][2][u];
        const float Syx = acc[1][0][u], Syy = acc[1][1][u], Syz = acc[1][2][u];
        const float Szx = acc[2][0][u], Szy = acc[2][1][u], Szz = acc[2][2][u];
        const float F00 =  Sxx + Syy + Szz;
        const float F11 =  Sxx - Syy - Szz;
        const float F22 = -Sxx + Syy - Szz;
        const float F33 = -Sxx - Syy + Szz;
        const float F01 = Syz - Szy;
        const float F02 = Szx - Sxz;
        const float F03 = Sxy - Syx;
        const float F12 = Sxy + Syx;
        const float F13 = Sxz + Szx;
        const float F23 = Syz + Szy;
        const float fro = sqrtf(F00 * F00 + F11 * F11 + F22 * F22 + F33 * F33 +
                                2.0f * (F01 * F01 + F02 * F02 + F03 * F03 +
                                        F12 * F12 + F13 * F13 + F23 * F23));
        P[u][0] = F00 + fro;
        P[u][1] = F11 + fro;
        P[u][2] = F22 + fro;
        P[u][3] = F33 + fro;
        P[u][4] = F01; P[u][5] = F02; P[u][6] = F03;
        P[u][7] = F12; P[u][8] = F13; P[u][9] = F23;
        P[u][10] = fro;
        vv[u][0] = 0.5f; vv[u][1] = 0.5f; vv[u][2] = 0.5f; vv[u][3] = 0.5f;
    }

    // 50 matvecs, normalize after every 5th (direction-preserving, fp32-safe:
    // spectral radius <= 2*fro so 5 unnormalized steps stay well in range)
    for (int blk = 0; blk < 10; ++blk) {
#pragma unroll
        for (int k = 0; k < 5; ++k) {
#pragma unroll
            for (int u = 0; u < 4; ++u) {
                const float* F = P[u];
                float* q = vv[u];
                const float w0 = F[0] * q[0] + F[4] * q[1] + F[5] * q[2] + F[6] * q[3];
                const float w1 = F[4] * q[0] + F[1] * q[1] + F[7] * q[2] + F[8] * q[3];
                const float w2 = F[5] * q[0] + F[7] * q[1] + F[2] * q[2] + F[9] * q[3];
                const float w3 = F[6] * q[0] + F[8] * q[1] + F[9] * q[2] + F[3] * q[3];
                q[0] = w0; q[1] = w1; q[2] = w2; q[3] = w3;
            }
        }
#pragma unroll
        for (int u = 0; u < 4; ++u) {
            float* q = vv[u];
            const float nn = q[0] * q[0] + q[1] * q[1] + q[2] * q[2] + q[3] * q[3];
            const float sc = __builtin_amdgcn_rsqf(nn);
            q[0] *= sc; q[1] *= sc; q[2] *= sc; q[3] *= sc;
        }
    }

    const float inv_na = 1.0f / (128.0f + 1e-5f);
    const float Gb = norm_t[tBase + nrow];
#pragma unroll
    for (int u = 0; u < 4; ++u) {
        const int srow = sBase + kgrp * 4 + u;
        const float Ga = norm_s[srow];
        const float* F = P[u];
        const float* q = vv[u];
        // Rayleigh quotient: (q^T F_shift q)/(q^T q) - fro
        const float m0 = F[0] * q[0] + F[4] * q[1] + F[5] * q[2] + F[6] * q[3];
        const float m1 = F[4] * q[0] + F[1] * q[1] + F[7] * q[2] + F[8] * q[3];
        const float m2 = F[5] * q[0] + F[7] * q[1] + F[2] * q[2] + F[9] * q[3];
        const float m3 = F[6] * q[0] + F[8] * q[1] + F[9] * q[2] + F[3] * q[3];
        const float num = q[0] * m0 + q[1] * m1 + q[2] * m2 + q[3] * m3;
        const float den = q[0] * q[0] + q[1] * q[1] + q[2] * q[2] + q[3] * q[3];
        const float eig = num * __builtin_amdgcn_rcpf(den) - F[10];
        float sq = (Ga + Gb - 2.0f * eig) * inv_na;
        out[(size_t)srow * NT + tBase + nrow] = sqrtf(fmaxf(sq, 0.0f));
    }
}

extern "C" void kernel_launch(void* const* d_in, const int* in_sizes, int n_in,
                              void* d_out, int out_size, void* d_ws, size_t ws_size,
                              hipStream_t stream) {
    const float* Xm = (const float*)d_in[0];
    const float* Xt = (const float*)d_in[1];
    float* out = (float*)d_out;

    unsigned short* ws16 = (unsigned short*)d_ws;
    unsigned short* Ahi = ws16;
    unsigned short* Alo = Ahi + (size_t)NS * 384;
    unsigned short* Bhi = Alo + (size_t)NS * 384;
    unsigned short* Blo = Bhi + (size_t)NT * 384;
    float* norm_m = (float*)(Blo + (size_t)NT * 384);
    float* norm_t = norm_m + NS;

    center_bf16_kernel<<<NS, 64, 0, stream>>>(Xm, Ahi, Alo, norm_m);
    center_bf16_kernel<<<NT, 64, 0, stream>>>(Xt, Bhi, Blo, norm_t);

    dim3 grid(NS / 16, NT / 64);
    pair_mfma_kernel<<<grid, 256, 0, stream>>>(Ahi, Alo, Bhi, Blo,
                                               norm_m, norm_t, out);
}

// Round 6
// 128.191 us; speedup vs baseline: 3.7366x; 1.1705x over previous
//
#include <hip/hip_runtime.h>
#include <math.h>

#define NS 2048
#define NT 2048
#define NATOMS 128

typedef __attribute__((ext_vector_type(8))) short bf16x8;
typedef __attribute__((ext_vector_type(4))) float f32x4;
typedef __attribute__((ext_vector_type(2))) float f32x2;

static __device__ __forceinline__ unsigned short f2bf(float f) {
    unsigned int u = __float_as_uint(f);
    unsigned int r = (u + 0x7fffu + ((u >> 16) & 1u)) >> 16;  // RNE
    return (unsigned short)r;
}
static __device__ __forceinline__ float bf2f(unsigned short h) {
    return __uint_as_float(((unsigned int)h) << 16);
}

// ---------------- Stage A: center + hi/lo bf16 split + squared norms ----------------
__global__ __launch_bounds__(64) void center_bf16_kernel(
    const float* __restrict__ X, unsigned short* __restrict__ Hi,
    unsigned short* __restrict__ Lo, float* __restrict__ norms)
{
    const int s = blockIdx.x;
    const int lane = threadIdx.x;  // 64 lanes, 2 atoms each
    const float* xs = X + (size_t)s * (NATOMS * 3);
    float x0 = xs[lane * 3 + 0];
    float y0 = xs[lane * 3 + 1];
    float z0 = xs[lane * 3 + 2];
    float x1 = xs[(lane + 64) * 3 + 0];
    float y1 = xs[(lane + 64) * 3 + 1];
    float z1 = xs[(lane + 64) * 3 + 2];
    float sx = x0 + x1, sy = y0 + y1, sz = z0 + z1;
#pragma unroll
    for (int off = 32; off > 0; off >>= 1) {
        sx += __shfl_xor(sx, off);
        sy += __shfl_xor(sy, off);
        sz += __shfl_xor(sz, off);
    }
    const float inv_n = 1.0f / (float)NATOMS;
    const float mx = sx * inv_n, my = sy * inv_n, mz = sz * inv_n;
    x0 -= mx; y0 -= my; z0 -= mz;
    x1 -= mx; y1 -= my; z1 -= mz;

    const size_t base = (size_t)s * 384;   // [s][3][128] bf16
    const float v[3][2] = {{x0, x1}, {y0, y1}, {z0, z1}};
#pragma unroll
    for (int c = 0; c < 3; ++c)
#pragma unroll
        for (int h = 0; h < 2; ++h) {
            const unsigned short hb = f2bf(v[c][h]);
            const unsigned short lb = f2bf(v[c][h] - bf2f(hb));
            Hi[base + c * 128 + h * 64 + lane] = hb;
            Lo[base + c * 128 + h * 64 + lane] = lb;
        }

    float nsq = x0 * x0 + y0 * y0 + z0 * z0 + x1 * x1 + y1 * y1 + z1 * z1;
#pragma unroll
    for (int off = 32; off > 0; off >>= 1) nsq += __shfl_xor(nsq, off);
    if (lane == 0) norms[s] = nsq;
}

// ---------------- Stage B: MFMA covariance + per-lane packed power iteration ----------------
__global__ __launch_bounds__(256, 1) void pair_mfma_kernel(
    const unsigned short* __restrict__ Ahi, const unsigned short* __restrict__ Alo,
    const unsigned short* __restrict__ Bhi, const unsigned short* __restrict__ Blo,
    const float* __restrict__ norm_s, const float* __restrict__ norm_t,
    float* __restrict__ out)
{
    const int tid = threadIdx.x;
    const int wave = tid >> 6;
    const int lane = tid & 63;
    const int nrow = lane & 15;   // A m-row / B n-col / C col
    const int kgrp = lane >> 4;   // k-octet selector
    const int sBase = blockIdx.x * 16;
    const int tBase = blockIdx.y * 64 + wave * 16;

    const size_t aOff = (size_t)(sBase + nrow) * 384 + kgrp * 8;
    const size_t bOff = (size_t)(tBase + nrow) * 384 + kgrp * 8;

    f32x4 acc[3][3];
#pragma unroll
    for (int i = 0; i < 3; ++i)
#pragma unroll
        for (int j = 0; j < 3; ++j) acc[i][j] = (f32x4){0.f, 0.f, 0.f, 0.f};

#pragma unroll
    for (int ks = 0; ks < 4; ++ks) {
        bf16x8 ah[3], al[3], bh[3], bl[3];
#pragma unroll
        for (int c = 0; c < 3; ++c) {
            ah[c] = *reinterpret_cast<const bf16x8*>(Ahi + aOff + c * 128 + ks * 32);
            al[c] = *reinterpret_cast<const bf16x8*>(Alo + aOff + c * 128 + ks * 32);
            bh[c] = *reinterpret_cast<const bf16x8*>(Bhi + bOff + c * 128 + ks * 32);
            bl[c] = *reinterpret_cast<const bf16x8*>(Blo + bOff + c * 128 + ks * 32);
        }
#pragma unroll
        for (int i = 0; i < 3; ++i)
#pragma unroll
            for (int j = 0; j < 3; ++j)
                acc[i][j] = __builtin_amdgcn_mfma_f32_16x16x32_bf16(
                    ah[i], bh[j], acc[i][j], 0, 0, 0);
#pragma unroll
        for (int i = 0; i < 3; ++i)
#pragma unroll
            for (int j = 0; j < 3; ++j)
                acc[i][j] = __builtin_amdgcn_mfma_f32_16x16x32_bf16(
                    ah[i], bl[j], acc[i][j], 0, 0, 0);
#pragma unroll
        for (int i = 0; i < 3; ++i)
#pragma unroll
            for (int j = 0; j < 3; ++j)
                acc[i][j] = __builtin_amdgcn_mfma_f32_16x16x32_bf16(
                    al[i], bh[j], acc[i][j], 0, 0, 0);
    }

    // ---- Per-lane: shifted F (R4 trajectory), packed matvec, normalize every 5 ----
    // Row pairs:
    //   FP0=(F00,F01) FP1=(F01,F11) FP2=(F02,F12) FP3=(F03,F13)  -> (w0,w1)
    //   FP4=(F02,F03) FP5=(F12,F13) FP6=(F22,F23) FP7=(F23,F33)  -> (w2,w3)
    // Diagonal entries carry the +fro shift, exactly as R4.
    f32x2 FP[4][8];
    f32x2 Q01[4], Q23[4];
    float FRO[4];
#pragma unroll
    for (int u = 0; u < 4; ++u) {
        const float Sxx = acc[0][0][u], Sxy = acc[0][1][u], Sxz = acc[0][2][u];
        const float Syx = acc[1][0][u], Syy = acc[1][1][u], Syz = acc[1][2][u];
        const float Szx = acc[2][0][u], Szy = acc[2][1][u], Szz = acc[2][2][u];
        const float F00 =  Sxx + Syy + Szz;
        const float F11 =  Sxx - Syy - Szz;
        const float F22 = -Sxx + Syy - Szz;
        const float F33 = -Sxx - Syy + Szz;
        const float F01 = Syz - Szy;
        const float F02 = Szx - Sxz;
        const float F03 = Sxy - Syx;
        const float F12 = Sxy + Syx;
        const float F13 = Sxz + Szx;
        const float F23 = Syz + Szy;
        const float fro = sqrtf(F00 * F00 + F11 * F11 + F22 * F22 + F33 * F33 +
                                2.0f * (F01 * F01 + F02 * F02 + F03 * F03 +
                                        F12 * F12 + F13 * F13 + F23 * F23));
        FRO[u] = fro;
        FP[u][0] = (f32x2){F00 + fro, F01};
        FP[u][1] = (f32x2){F01, F11 + fro};
        FP[u][2] = (f32x2){F02, F12};
        FP[u][3] = (f32x2){F03, F13};
        FP[u][4] = (f32x2){F02, F03};
        FP[u][5] = (f32x2){F12, F13};
        FP[u][6] = (f32x2){F22 + fro, F23};
        FP[u][7] = (f32x2){F23, F33 + fro};
        Q01[u] = (f32x2){0.5f, 0.5f};
        Q23[u] = (f32x2){0.5f, 0.5f};
    }

    // 50 matvecs, normalize after every 5th (identical op order to R4's
    // scalar version: mul + 3 contracted fma per output component).
    for (int blk = 0; blk < 10; ++blk) {
#pragma unroll
        for (int k = 0; k < 5; ++k) {
#pragma unroll
            for (int u = 0; u < 4; ++u) {
                f32x2 w01, w23;
                asm("v_pk_mul_f32 %0, %1, %2 op_sel:[0,0] op_sel_hi:[1,0]"
                    : "=v"(w01) : "v"(FP[u][0]), "v"(Q01[u]));
                asm("v_pk_fma_f32 %0, %1, %2, %0 op_sel:[0,1,0] op_sel_hi:[1,1,1]"
                    : "+v"(w01) : "v"(FP[u][1]), "v"(Q01[u]));
                asm("v_pk_fma_f32 %0, %1, %2, %0 op_sel:[0,0,0] op_sel_hi:[1,0,1]"
                    : "+v"(w01) : "v"(FP[u][2]), "v"(Q23[u]));
                asm("v_pk_fma_f32 %0, %1, %2, %0 op_sel:[0,1,0] op_sel_hi:[1,1,1]"
                    : "+v"(w01) : "v"(FP[u][3]), "v"(Q23[u]));
                asm("v_pk_mul_f32 %0, %1, %2 op_sel:[0,0] op_sel_hi:[1,0]"
                    : "=v"(w23) : "v"(FP[u][4]), "v"(Q01[u]));
                asm("v_pk_fma_f32 %0, %1, %2, %0 op_sel:[0,1,0] op_sel_hi:[1,1,1]"
                    : "+v"(w23) : "v"(FP[u][5]), "v"(Q01[u]));
                asm("v_pk_fma_f32 %0, %1, %2, %0 op_sel:[0,0,0] op_sel_hi:[1,0,1]"
                    : "+v"(w23) : "v"(FP[u][6]), "v"(Q23[u]));
                asm("v_pk_fma_f32 %0, %1, %2, %0 op_sel:[0,1,0] op_sel_hi:[1,1,1]"
                    : "+v"(w23) : "v"(FP[u][7]), "v"(Q23[u]));
                Q01[u] = w01;
                Q23[u] = w23;
            }
        }
#pragma unroll
        for (int u = 0; u < 4; ++u) {
            const float q0 = Q01[u].x, q1 = Q01[u].y;
            const float q2 = Q23[u].x, q3 = Q23[u].y;
            const float nn = q0 * q0 + q1 * q1 + q2 * q2 + q3 * q3;
            const float sc = __builtin_amdgcn_rsqf(nn);
            Q01[u].x = q0 * sc; Q01[u].y = q1 * sc;
            Q23[u].x = q2 * sc; Q23[u].y = q3 * sc;
        }
    }

    const float inv_na = 1.0f / (128.0f + 1e-5f);
    const float Gb = norm_t[tBase + nrow];
#pragma unroll
    for (int u = 0; u < 4; ++u) {
        const int srow = sBase + kgrp * 4 + u;
        const float Ga = norm_s[srow];
        const float q0 = Q01[u].x, q1 = Q01[u].y, q2 = Q23[u].x, q3 = Q23[u].y;
        // Rayleigh: (q^T F_shift q)/(q^T q) - fro  (R4-identical)
        const float m0 = FP[u][0].x * q0 + FP[u][1].x * q1 + FP[u][2].x * q2 + FP[u][3].x * q3;
        const float m1 = FP[u][0].y * q0 + FP[u][1].y * q1 + FP[u][2].y * q2 + FP[u][3].y * q3;
        const float m2 = FP[u][4].x * q0 + FP[u][5].x * q1 + FP[u][6].x * q2 + FP[u][7].x * q3;
        const float m3 = FP[u][4].y * q0 + FP[u][5].y * q1 + FP[u][6].y * q2 + FP[u][7].y * q3;
        const float num = q0 * m0 + q1 * m1 + q2 * m2 + q3 * m3;
        const float den = q0 * q0 + q1 * q1 + q2 * q2 + q3 * q3;
        const float eig = num * __builtin_amdgcn_rcpf(den) - FRO[u];
        float sq = (Ga + Gb - 2.0f * eig) * inv_na;
        out[(size_t)srow * NT + tBase + nrow] = sqrtf(fmaxf(sq, 0.0f));
    }
}

extern "C" void kernel_launch(void* const* d_in, const int* in_sizes, int n_in,
                              void* d_out, int out_size, void* d_ws, size_t ws_size,
                              hipStream_t stream) {
    const float* Xm = (const float*)d_in[0];
    const float* Xt = (const float*)d_in[1];
    float* out = (float*)d_out;

    unsigned short* ws16 = (unsigned short*)d_ws;
    unsigned short* Ahi = ws16;
    unsigned short* Alo = Ahi + (size_t)NS * 384;
    unsigned short* Bhi = Alo + (size_t)NS * 384;
    unsigned short* Blo = Bhi + (size_t)NT * 384;
    float* norm_m = (float*)(Blo + (size_t)NT * 384);
    float* norm_t = norm_m + NS;

    center_bf16_kernel<<<NS, 64, 0, stream>>>(Xm, Ahi, Alo, norm_m);
    center_bf16_kernel<<<NT, 64, 0, stream>>>(Xt, Bhi, Blo, norm_t);

    dim3 grid(NS / 16, NT / 64);
    pair_mfma_kernel<<<grid, 256, 0, stream>>>(Ahi, Alo, Bhi, Blo,
                                               norm_m, norm_t, out);
}